// Round 1
// baseline (1692.294 us; speedup 1.0000x reference)
//
#include <hip/hip_runtime.h>
#include <math.h>

#define N_NODES 50000
#define N_EDGES 800000
#define D 128
#define N_GRAPHS 64
#define EPS 1e-5f

static inline size_t align256(size_t x) { return (x + 255) & ~(size_t)255; }

// ---------------- GEMM: K,Q,V,S = X @ [Wk|Wq|Wv|Ws] + biases ----------------
// grid: N/8 blocks, 128 threads. Each block computes 8 rows x 512 cols.
__global__ void gemm_kqvs(const float* __restrict__ X,
                          const float* __restrict__ Wk, const float* __restrict__ bk,
                          const float* __restrict__ Wq, const float* __restrict__ bq,
                          const float* __restrict__ Wv, const float* __restrict__ bv,
                          const float* __restrict__ Ws, const float* __restrict__ bs,
                          float* __restrict__ Kb, float* __restrict__ Qb,
                          float* __restrict__ Vb, float* __restrict__ Sb)
{
    __shared__ float xs[8][D];
    const int j = threadIdx.x;           // 0..127 output column within each W
    const int n0 = blockIdx.x * 8;
    #pragma unroll
    for (int r = 0; r < 8; ++r) {
        xs[r][j] = X[(size_t)(n0 + r) * D + j];
    }
    __syncthreads();
    float accK[8], accQ[8], accV[8], accS[8];
    #pragma unroll
    for (int r = 0; r < 8; ++r) { accK[r] = 0.f; accQ[r] = 0.f; accV[r] = 0.f; accS[r] = 0.f; }
    #pragma unroll 4
    for (int k = 0; k < D; ++k) {
        const float wk = Wk[k * D + j];
        const float wq = Wq[k * D + j];
        const float wv = Wv[k * D + j];
        const float ws = Ws[k * D + j];
        #pragma unroll
        for (int r = 0; r < 8; ++r) {
            const float xv = xs[r][k];
            accK[r] = fmaf(xv, wk, accK[r]);
            accQ[r] = fmaf(xv, wq, accQ[r]);
            accV[r] = fmaf(xv, wv, accV[r]);
            accS[r] = fmaf(xv, ws, accS[r]);
        }
    }
    const float bkv = bk[j], bqv = bq[j], bvv = bv[j], bsv = bs[j];
    #pragma unroll
    for (int r = 0; r < 8; ++r) {
        const size_t n = (size_t)(n0 + r);
        Kb[n * D + j] = accK[r] + bkv;
        Qb[n * D + j] = accQ[r] + bqv;
        Vb[n * D + j] = accV[r] + bvv;
        Sb[n * D + j] = accS[r] + bsv;
    }
}

// ---------------- CSR build ----------------
__global__ void hist_dst(const int* __restrict__ dst, int* __restrict__ cnt) {
    int e = blockIdx.x * blockDim.x + threadIdx.x;
    if (e < N_EDGES) atomicAdd(&cnt[dst[e]], 1);
}

__global__ void scan_rows(const int* __restrict__ cnt, int* __restrict__ row_start) {
    __shared__ int partial[1024];
    const int T = 1024;
    const int t = threadIdx.x;
    const int chunk = (N_NODES + T - 1) / T;
    const int lo = t * chunk;
    const int hi = min(lo + chunk, N_NODES);
    int s = 0;
    for (int i = lo; i < hi; ++i) s += cnt[i];
    partial[t] = s;
    __syncthreads();
    for (int off = 1; off < T; off <<= 1) {
        int add = (t >= off) ? partial[t - off] : 0;
        __syncthreads();
        partial[t] += add;
        __syncthreads();
    }
    int base = (t == 0) ? 0 : partial[t - 1];
    for (int i = lo; i < hi; ++i) {
        row_start[i] = base;
        base += cnt[i];
    }
    if (t == T - 1) row_start[N_NODES] = partial[T - 1];
}

__global__ void copy_ints(const int* __restrict__ a, int* __restrict__ b, int n) {
    int i = blockIdx.x * blockDim.x + threadIdx.x;
    if (i < n) b[i] = a[i];
}

__global__ void fill_csr(const int* __restrict__ src, const int* __restrict__ dst,
                         int* __restrict__ cursor, int* __restrict__ col) {
    int e = blockIdx.x * blockDim.x + threadIdx.x;
    if (e < N_EDGES) {
        int d = dst[e];
        int p = atomicAdd(&cursor[d], 1);
        col[p] = src[e];
    }
}

// ---------------- Edge aggregation + skip + ReLU ----------------
// block 256 threads = 2 dst nodes; thread handles one feature dim.
__global__ void aggregate(const float* __restrict__ Kb, const float* __restrict__ Qb,
                          const float* __restrict__ Vb, const float* __restrict__ Sb,
                          const int* __restrict__ row_start, const int* __restrict__ col,
                          float* __restrict__ H)
{
    const int tid = threadIdx.x;
    const int node = blockIdx.x * 2 + (tid >> 7);
    const int d = tid & 127;
    const float kd = Kb[(size_t)node * D + d];
    float acc = 0.f;
    const int e0 = row_start[node];
    const int e1 = row_start[node + 1];
    for (int e = e0; e < e1; ++e) {
        const int s = col[e];
        const float qd = Qb[(size_t)s * D + d];
        const float vd = Vb[(size_t)s * D + d];
        const float z = kd + qd;
        const float gate = 1.0f / (1.0f + __expf(-z));
        acc = fmaf(gate, vd, acc);
    }
    H[(size_t)node * D + d] = fmaxf(acc + Sb[(size_t)node * D + d], 0.0f);
}

// ---------------- BatchNorm over nodes ----------------
__global__ void bn_stats(const float* __restrict__ H, float* __restrict__ fsum,
                         float* __restrict__ fsq)
{
    __shared__ float s1[256], s2[256];
    const int tid = threadIdx.x;
    const int d = tid & 127;
    const int rowoff = tid >> 7;
    float sum = 0.f, sq = 0.f;
    for (int n = blockIdx.x * 2 + rowoff; n < N_NODES; n += gridDim.x * 2) {
        const float v = H[(size_t)n * D + d];
        sum += v; sq += v * v;
    }
    s1[tid] = sum; s2[tid] = sq;
    __syncthreads();
    if (tid < 128) {
        atomicAdd(&fsum[d], s1[tid] + s1[tid + 128]);
        atomicAdd(&fsq[d],  s2[tid] + s2[tid + 128]);
    }
}

__global__ void bn_apply(float* __restrict__ H, const float* __restrict__ fsum,
                         const float* __restrict__ fsq, const float* __restrict__ g,
                         const float* __restrict__ b)
{
    const int idx = blockIdx.x * blockDim.x + threadIdx.x;
    const int total = N_NODES * D / 4;
    if (idx >= total) return;
    float4 h = ((const float4*)H)[idx];
    float hv[4] = {h.x, h.y, h.z, h.w};
    const int dbase = (idx * 4) & 127;
    float o[4];
    #pragma unroll
    for (int c = 0; c < 4; ++c) {
        const int d = dbase + c;
        const float mu = fsum[d] * (1.0f / N_NODES);
        const float var = fsq[d] * (1.0f / N_NODES) - mu * mu;
        const float sc = g[d] * rsqrtf(var + EPS);
        o[c] = (hv[c] - mu) * sc + b[d];
    }
    ((float4*)H)[idx] = make_float4(o[0], o[1], o[2], o[3]);
}

// ---------------- Pooling ----------------
__global__ void hist_batch(const int* __restrict__ batch, int* __restrict__ gcnt) {
    int n = blockIdx.x * blockDim.x + threadIdx.x;
    if (n < N_NODES) atomicAdd(&gcnt[batch[n]], 1);
}

__global__ void scan_graphs(const int* __restrict__ gcnt, int* __restrict__ gstart) {
    if (threadIdx.x == 0 && blockIdx.x == 0) {
        int s = 0;
        for (int g = 0; g < N_GRAPHS; ++g) { gstart[g] = s; s += gcnt[g]; }
        gstart[N_GRAPHS] = s;
    }
}

__global__ void pool(const float* __restrict__ X, const int* __restrict__ gstart,
                     float* __restrict__ gap, float* __restrict__ gsp)
{
    const int g = blockIdx.x;      // 64
    const int d = threadIdx.x;     // 128
    const int lo = gstart[g], hi = gstart[g + 1];
    float sum = 0.f, mx = -INFINITY;
    for (int n = lo; n < hi; ++n) {
        const float v = X[(size_t)n * D + d];
        sum += v;
        mx = fmaxf(mx, v);
    }
    const int cnt = hi - lo;
    gap[g * D + d] = sum / fmaxf((float)cnt, 1.0f);
    gsp[g * D + d] = (cnt > 0) ? mx : 0.0f;
}

// ---------------- BN over rows (small) ----------------
__global__ void bn_rows(const float* __restrict__ A, int rows, int cols,
                        const float* __restrict__ g, const float* __restrict__ b,
                        float* __restrict__ out, int out_cols, int out_off)
{
    const int c = blockIdx.x * blockDim.x + threadIdx.x;
    if (c >= cols) return;
    float sum = 0.f, sq = 0.f;
    for (int r = 0; r < rows; ++r) {
        const float v = A[r * cols + c];
        sum += v; sq += v * v;
    }
    const float mu = sum / rows;
    const float var = sq / rows - mu * mu;
    const float sc = g[c] * rsqrtf(var + EPS);
    const float sh = b[c] - mu * sc;
    for (int r = 0; r < rows; ++r) {
        out[r * out_cols + out_off + c] = A[r * cols + c] * sc + sh;
    }
}

// ---------------- small GEMM: out = [relu](A @ W + bias) ----------------
// grid = rows, block = 256 (>= C, >= staging for K<=256)
__global__ void gemm_small(const float* __restrict__ A, const float* __restrict__ W,
                           const float* __restrict__ bias, float* __restrict__ out,
                           int K, int C, int relu)
{
    __shared__ float as[256];
    const int r = blockIdx.x;
    for (int k = threadIdx.x; k < K; k += blockDim.x) as[k] = A[r * K + k];
    __syncthreads();
    const int j = threadIdx.x;
    if (j < C) {
        float acc = bias[j];
        for (int k = 0; k < K; ++k) acc = fmaf(as[k], W[k * C + j], acc);
        if (relu) acc = fmaxf(acc, 0.f);
        out[r * C + j] = acc;
    }
}

extern "C" void kernel_launch(void* const* d_in, const int* in_sizes, int n_in,
                              void* d_out, int out_size, void* d_ws, size_t ws_size,
                              hipStream_t stream)
{
    const float* x     = (const float*)d_in[0];
    const int*   ei    = (const int*)d_in[1];
    const int*   srcE  = ei;                // edge_index[0]
    const int*   dstE  = ei + N_EDGES;      // edge_index[1]
    const int*   batch = (const int*)d_in[2];
    const float* Wk = (const float*)d_in[3];  const float* bk = (const float*)d_in[4];
    const float* Wq = (const float*)d_in[5];  const float* bq = (const float*)d_in[6];
    const float* Wv = (const float*)d_in[7];  const float* bv = (const float*)d_in[8];
    const float* Ws = (const float*)d_in[9];  const float* bs = (const float*)d_in[10];
    const float* g_cl = (const float*)d_in[11]; const float* b_cl = (const float*)d_in[12];
    const float* g_gap = (const float*)d_in[13]; const float* b_gap = (const float*)d_in[14];
    const float* g_gsp = (const float*)d_in[15]; const float* b_gsp = (const float*)d_in[16];
    const float* W1 = (const float*)d_in[17]; const float* b1 = (const float*)d_in[18];
    const float* g1 = (const float*)d_in[19]; const float* bt1 = (const float*)d_in[20];
    const float* W2 = (const float*)d_in[21]; const float* b2 = (const float*)d_in[22];
    const float* g2 = (const float*)d_in[23]; const float* bt2 = (const float*)d_in[24];
    const float* Wl = (const float*)d_in[25]; const float* bl = (const float*)d_in[26];
    float* out = (float*)d_out;

    // ---- workspace carve ----
    char* ws = (char*)d_ws;
    size_t off = 0;
    const size_t bufB = (size_t)N_NODES * D * sizeof(float);   // 25.6 MB
    float* Kb = (float*)(ws + off); off = align256(off + bufB);
    float* Qb = (float*)(ws + off); off = align256(off + bufB);
    float* Vb = (float*)(ws + off); off = align256(off + bufB);
    float* Sb = (float*)(ws + off); off = align256(off + bufB);
    float* H  = (float*)(ws + off); off = align256(off + bufB);   // persistent node features
    float* fsum = (float*)(ws + off); off = align256(off + 128 * sizeof(float));
    float* fsq  = (float*)(ws + off); off = align256(off + 128 * sizeof(float));
    int* cnt       = (int*)(ws + off); off = align256(off + (size_t)N_NODES * sizeof(int));
    int* row_start = (int*)(ws + off); off = align256(off + (size_t)(N_NODES + 1) * sizeof(int));
    int* cursor    = (int*)(ws + off); off = align256(off + (size_t)(N_NODES + 1) * sizeof(int));
    int* colI      = (int*)(ws + off); off = align256(off + (size_t)N_EDGES * sizeof(int));
    int* gcnt      = (int*)(ws + off); off = align256(off + (N_GRAPHS) * sizeof(int));
    int* gstart    = (int*)(ws + off); off = align256(off + (N_GRAPHS + 1) * sizeof(int));
    float* gap = (float*)(ws + off); off = align256(off + (size_t)N_GRAPHS * D * sizeof(float));
    float* gsp = (float*)(ws + off); off = align256(off + (size_t)N_GRAPHS * D * sizeof(float));
    float* h0  = (float*)(ws + off); off = align256(off + (size_t)N_GRAPHS * 256 * sizeof(float));
    float* h1  = (float*)(ws + off); off = align256(off + (size_t)N_GRAPHS * 256 * sizeof(float));
    float* h2  = (float*)(ws + off); off = align256(off + (size_t)N_GRAPHS * 128 * sizeof(float));
    if (off > ws_size) return;  // insufficient workspace -> will fail validation visibly

    // ---- CSR build (once; reused across the 3 layers) ----
    hipMemsetAsync(cnt, 0, (size_t)N_NODES * sizeof(int), stream);
    hipMemsetAsync(gcnt, 0, N_GRAPHS * sizeof(int), stream);
    hist_dst<<<(N_EDGES + 255) / 256, 256, 0, stream>>>(dstE, cnt);
    scan_rows<<<1, 1024, 0, stream>>>(cnt, row_start);
    copy_ints<<<(N_NODES + 1 + 255) / 256, 256, 0, stream>>>(row_start, cursor, N_NODES + 1);
    fill_csr<<<(N_EDGES + 255) / 256, 256, 0, stream>>>(srcE, dstE, cursor, colI);
    hist_batch<<<(N_NODES + 255) / 256, 256, 0, stream>>>(batch, gcnt);
    scan_graphs<<<1, 64, 0, stream>>>(gcnt, gstart);

    // ---- 3 conv layers ----
    for (int i = 0; i < 3; ++i) {
        const float* Xin = (i == 0) ? x : H;
        gemm_kqvs<<<N_NODES / 8, 128, 0, stream>>>(
            Xin,
            Wk + (size_t)i * D * D, bk + i * D,
            Wq + (size_t)i * D * D, bq + i * D,
            Wv + (size_t)i * D * D, bv + i * D,
            Ws + (size_t)i * D * D, bs + i * D,
            Kb, Qb, Vb, Sb);
        aggregate<<<N_NODES / 2, 256, 0, stream>>>(Kb, Qb, Vb, Sb, row_start, colI, H);
        hipMemsetAsync(fsum, 0, 128 * sizeof(float), stream);
        hipMemsetAsync(fsq, 0, 128 * sizeof(float), stream);
        bn_stats<<<256, 256, 0, stream>>>(H, fsum, fsq);
        bn_apply<<<(N_NODES * D / 4 + 255) / 256, 256, 0, stream>>>(
            H, fsum, fsq, g_cl + i * D, b_cl + i * D);
    }

    // ---- pooling ----
    pool<<<N_GRAPHS, 128, 0, stream>>>(H, gstart, gap, gsp);
    bn_rows<<<1, 128, 0, stream>>>(gap, N_GRAPHS, 128, g_gap, b_gap, h0, 256, 0);
    bn_rows<<<1, 128, 0, stream>>>(gsp, N_GRAPHS, 128, g_gsp, b_gsp, h0, 256, 128);

    // ---- MLP head ----
    gemm_small<<<N_GRAPHS, 256, 0, stream>>>(h0, W1, b1, h1, 256, 256, 1);
    bn_rows<<<1, 256, 0, stream>>>(h1, N_GRAPHS, 256, g1, bt1, h1, 256, 0);
    gemm_small<<<N_GRAPHS, 256, 0, stream>>>(h1, W2, b2, h2, 256, 128, 1);
    bn_rows<<<1, 128, 0, stream>>>(h2, N_GRAPHS, 128, g2, bt2, h2, 128, 0);
    gemm_small<<<N_GRAPHS, 256, 0, stream>>>(h2, Wl, bl, out, 128, 5, 0);
}

// Round 2
// 1488.279 us; speedup vs baseline: 1.1371x; 1.1371x over previous
//
#include <hip/hip_runtime.h>
#include <math.h>

#define N_NODES 50000
#define N_EDGES 800000
#define D 128
#define N_GRAPHS 64
#define EPS 1e-5f

static inline size_t align256(size_t x) { return (x + 255) & ~(size_t)255; }

// ---------------- GEMM: K,Q,V,S = X @ [Wk|Wq|Wv|Ws] + biases ----------------
// grid: N/8 blocks, 128 threads. Each block computes 8 rows x 512 cols.
__global__ void gemm_kqvs(const float* __restrict__ X,
                          const float* __restrict__ Wk, const float* __restrict__ bk,
                          const float* __restrict__ Wq, const float* __restrict__ bq,
                          const float* __restrict__ Wv, const float* __restrict__ bv,
                          const float* __restrict__ Ws, const float* __restrict__ bs,
                          float* __restrict__ Kb, float* __restrict__ Qb,
                          float* __restrict__ Vb, float* __restrict__ Sb)
{
    __shared__ float xs[8][D];
    const int j = threadIdx.x;           // 0..127 output column within each W
    const int n0 = blockIdx.x * 8;
    #pragma unroll
    for (int r = 0; r < 8; ++r) {
        xs[r][j] = X[(size_t)(n0 + r) * D + j];
    }
    __syncthreads();
    float accK[8], accQ[8], accV[8], accS[8];
    #pragma unroll
    for (int r = 0; r < 8; ++r) { accK[r] = 0.f; accQ[r] = 0.f; accV[r] = 0.f; accS[r] = 0.f; }
    #pragma unroll 4
    for (int k = 0; k < D; ++k) {
        const float wk = Wk[k * D + j];
        const float wq = Wq[k * D + j];
        const float wv = Wv[k * D + j];
        const float ws = Ws[k * D + j];
        #pragma unroll
        for (int r = 0; r < 8; ++r) {
            const float xv = xs[r][k];
            accK[r] = fmaf(xv, wk, accK[r]);
            accQ[r] = fmaf(xv, wq, accQ[r]);
            accV[r] = fmaf(xv, wv, accV[r]);
            accS[r] = fmaf(xv, ws, accS[r]);
        }
    }
    const float bkv = bk[j], bqv = bq[j], bvv = bv[j], bsv = bs[j];
    #pragma unroll
    for (int r = 0; r < 8; ++r) {
        const size_t n = (size_t)(n0 + r);
        Kb[n * D + j] = accK[r] + bkv;
        Qb[n * D + j] = accQ[r] + bqv;
        Vb[n * D + j] = accV[r] + bvv;
        Sb[n * D + j] = accS[r] + bsv;
    }
}

// ---------------- CSR build ----------------
__global__ void hist_dst(const int* __restrict__ dst, int* __restrict__ cnt) {
    int e = blockIdx.x * blockDim.x + threadIdx.x;
    if (e < N_EDGES) atomicAdd(&cnt[dst[e]], 1);
}

// exclusive scan over cnt -> row_start AND cursor (both get the same values)
__global__ void scan_rows(const int* __restrict__ cnt, int* __restrict__ row_start,
                          int* __restrict__ cursor) {
    __shared__ int partial[1024];
    const int T = 1024;
    const int t = threadIdx.x;
    const int chunk = (N_NODES + T - 1) / T;
    const int lo = t * chunk;
    const int hi = min(lo + chunk, N_NODES);
    int s = 0;
    for (int i = lo; i < hi; ++i) s += cnt[i];
    partial[t] = s;
    __syncthreads();
    for (int off = 1; off < T; off <<= 1) {
        int add = (t >= off) ? partial[t - off] : 0;
        __syncthreads();
        partial[t] += add;
        __syncthreads();
    }
    int base = (t == 0) ? 0 : partial[t - 1];
    for (int i = lo; i < hi; ++i) {
        row_start[i] = base;
        cursor[i] = base;
        base += cnt[i];
    }
    if (t == T - 1) { row_start[N_NODES] = partial[T - 1]; cursor[N_NODES] = partial[T - 1]; }
}

__global__ void fill_csr(const int* __restrict__ src, const int* __restrict__ dst,
                         int* __restrict__ cursor, int* __restrict__ col) {
    int e = blockIdx.x * blockDim.x + threadIdx.x;
    if (e < N_EDGES) {
        int d = dst[e];
        int p = atomicAdd(&cursor[d], 1);
        col[p] = src[e];
    }
}

// ---------------- Edge aggregation + skip + ReLU ----------------
// block 256 threads = 2 dst nodes; thread handles one feature dim.
__global__ void aggregate(const float* __restrict__ Kb, const float* __restrict__ Qb,
                          const float* __restrict__ Vb, const float* __restrict__ Sb,
                          const int* __restrict__ row_start, const int* __restrict__ col,
                          float* __restrict__ H)
{
    const int tid = threadIdx.x;
    const int node = blockIdx.x * 2 + (tid >> 7);
    const int d = tid & 127;
    const float kd = Kb[(size_t)node * D + d];
    float acc = 0.f;
    const int e0 = row_start[node];
    const int e1 = row_start[node + 1];
    for (int e = e0; e < e1; ++e) {
        const int s = col[e];
        const float qd = Qb[(size_t)s * D + d];
        const float vd = Vb[(size_t)s * D + d];
        const float z = kd + qd;
        const float gate = 1.0f / (1.0f + __expf(-z));
        acc = fmaf(gate, vd, acc);
    }
    H[(size_t)node * D + d] = fmaxf(acc + Sb[(size_t)node * D + d], 0.0f);
}

// ---------------- BatchNorm over nodes ----------------
__global__ void bn_stats(const float* __restrict__ H, float* __restrict__ fsum,
                         float* __restrict__ fsq)
{
    __shared__ float s1[256], s2[256];
    const int tid = threadIdx.x;
    const int d = tid & 127;
    const int rowoff = tid >> 7;
    float sum = 0.f, sq = 0.f;
    for (int n = blockIdx.x * 2 + rowoff; n < N_NODES; n += gridDim.x * 2) {
        const float v = H[(size_t)n * D + d];
        sum += v; sq += v * v;
    }
    s1[tid] = sum; s2[tid] = sq;
    __syncthreads();
    if (tid < 128) {
        atomicAdd(&fsum[d], s1[tid] + s1[tid + 128]);
        atomicAdd(&fsq[d],  s2[tid] + s2[tid + 128]);
    }
}

__global__ void bn_apply(float* __restrict__ H, const float* __restrict__ fsum,
                         const float* __restrict__ fsq, const float* __restrict__ g,
                         const float* __restrict__ b)
{
    const int idx = blockIdx.x * blockDim.x + threadIdx.x;
    const int total = N_NODES * D / 4;
    if (idx >= total) return;
    float4 h = ((const float4*)H)[idx];
    float hv[4] = {h.x, h.y, h.z, h.w};
    const int dbase = (idx * 4) & 127;
    float o[4];
    #pragma unroll
    for (int c = 0; c < 4; ++c) {
        const int d = dbase + c;
        const float mu = fsum[d] * (1.0f / N_NODES);
        const float var = fsq[d] * (1.0f / N_NODES) - mu * mu;
        const float sc = g[d] * rsqrtf(var + EPS);
        o[c] = (hv[c] - mu) * sc + b[d];
    }
    ((float4*)H)[idx] = make_float4(o[0], o[1], o[2], o[3]);
}

// ---------------- Pooling ----------------
// batch is sorted: graph boundaries via binary search, no atomics.
__global__ void find_gstart(const int* __restrict__ batch, int* __restrict__ gstart) {
    const int g = threadIdx.x;
    if (g > N_GRAPHS) return;
    int lo = 0, hi = N_NODES;
    while (lo < hi) {
        int mid = (lo + hi) >> 1;
        if (batch[mid] < g) lo = mid + 1; else hi = mid;
    }
    gstart[g] = lo;   // first index with batch[i] >= g
}

__global__ void pool(const float* __restrict__ X, const int* __restrict__ gstart,
                     float* __restrict__ gap, float* __restrict__ gsp)
{
    const int g = blockIdx.x;      // 64
    const int d = threadIdx.x;     // 128
    const int lo = gstart[g], hi = gstart[g + 1];
    float sum = 0.f, mx = -INFINITY;
    for (int n = lo; n < hi; ++n) {
        const float v = X[(size_t)n * D + d];
        sum += v;
        mx = fmaxf(mx, v);
    }
    const int cnt = hi - lo;
    gap[g * D + d] = sum / fmaxf((float)cnt, 1.0f);
    gsp[g * D + d] = (cnt > 0) ? mx : 0.0f;
}

// ---------------- BN over rows (small) ----------------
__global__ void bn_rows(const float* __restrict__ A, int rows, int cols,
                        const float* __restrict__ g, const float* __restrict__ b,
                        float* __restrict__ out, int out_cols, int out_off)
{
    const int c = blockIdx.x * blockDim.x + threadIdx.x;
    if (c >= cols) return;
    float sum = 0.f, sq = 0.f;
    for (int r = 0; r < rows; ++r) {
        const float v = A[r * cols + c];
        sum += v; sq += v * v;
    }
    const float mu = sum / rows;
    const float var = sq / rows - mu * mu;
    const float sc = g[c] * rsqrtf(var + EPS);
    const float sh = b[c] - mu * sc;
    for (int r = 0; r < rows; ++r) {
        out[r * out_cols + out_off + c] = A[r * cols + c] * sc + sh;
    }
}

// ---------------- small GEMM: out = [relu](A @ W + bias) ----------------
// grid = rows, block = 256 (>= C, >= staging for K<=256)
__global__ void gemm_small(const float* __restrict__ A, const float* __restrict__ W,
                           const float* __restrict__ bias, float* __restrict__ out,
                           int K, int C, int relu)
{
    __shared__ float as[256];
    const int r = blockIdx.x;
    for (int k = threadIdx.x; k < K; k += blockDim.x) as[k] = A[r * K + k];
    __syncthreads();
    const int j = threadIdx.x;
    if (j < C) {
        float acc = bias[j];
        for (int k = 0; k < K; ++k) acc = fmaf(as[k], W[k * C + j], acc);
        if (relu) acc = fmaxf(acc, 0.f);
        out[r * C + j] = acc;
    }
}

extern "C" void kernel_launch(void* const* d_in, const int* in_sizes, int n_in,
                              void* d_out, int out_size, void* d_ws, size_t ws_size,
                              hipStream_t stream)
{
    const float* x     = (const float*)d_in[0];
    const int*   ei    = (const int*)d_in[1];
    const int*   srcE  = ei;                // edge_index[0]
    const int*   dstE  = ei + N_EDGES;      // edge_index[1]
    const int*   batch = (const int*)d_in[2];
    const float* Wk = (const float*)d_in[3];  const float* bk = (const float*)d_in[4];
    const float* Wq = (const float*)d_in[5];  const float* bq = (const float*)d_in[6];
    const float* Wv = (const float*)d_in[7];  const float* bv = (const float*)d_in[8];
    const float* Ws = (const float*)d_in[9];  const float* bs = (const float*)d_in[10];
    const float* g_cl = (const float*)d_in[11]; const float* b_cl = (const float*)d_in[12];
    const float* g_gap = (const float*)d_in[13]; const float* b_gap = (const float*)d_in[14];
    const float* g_gsp = (const float*)d_in[15]; const float* b_gsp = (const float*)d_in[16];
    const float* W1 = (const float*)d_in[17]; const float* b1 = (const float*)d_in[18];
    const float* g1 = (const float*)d_in[19]; const float* bt1 = (const float*)d_in[20];
    const float* W2 = (const float*)d_in[21]; const float* b2 = (const float*)d_in[22];
    const float* g2 = (const float*)d_in[23]; const float* bt2 = (const float*)d_in[24];
    const float* Wl = (const float*)d_in[25]; const float* bl = (const float*)d_in[26];
    float* out = (float*)d_out;

    // ---- workspace carve ----
    char* ws = (char*)d_ws;
    size_t off = 0;
    const size_t bufB = (size_t)N_NODES * D * sizeof(float);   // 25.6 MB
    float* Kb = (float*)(ws + off); off = align256(off + bufB);
    float* Qb = (float*)(ws + off); off = align256(off + bufB);
    float* Vb = (float*)(ws + off); off = align256(off + bufB);
    float* Sb = (float*)(ws + off); off = align256(off + bufB);
    float* H  = (float*)(ws + off); off = align256(off + bufB);   // persistent node features
    float* fsum = (float*)(ws + off); off = align256(off + 128 * sizeof(float));
    float* fsq  = (float*)(ws + off); off = align256(off + 128 * sizeof(float));
    int* cnt       = (int*)(ws + off); off = align256(off + (size_t)N_NODES * sizeof(int));
    int* row_start = (int*)(ws + off); off = align256(off + (size_t)(N_NODES + 1) * sizeof(int));
    int* cursor    = (int*)(ws + off); off = align256(off + (size_t)(N_NODES + 1) * sizeof(int));
    int* colI      = (int*)(ws + off); off = align256(off + (size_t)N_EDGES * sizeof(int));
    int* gstart    = (int*)(ws + off); off = align256(off + (N_GRAPHS + 1) * sizeof(int));
    float* gap = (float*)(ws + off); off = align256(off + (size_t)N_GRAPHS * D * sizeof(float));
    float* gsp = (float*)(ws + off); off = align256(off + (size_t)N_GRAPHS * D * sizeof(float));
    float* h0  = (float*)(ws + off); off = align256(off + (size_t)N_GRAPHS * 256 * sizeof(float));
    float* h1  = (float*)(ws + off); off = align256(off + (size_t)N_GRAPHS * 256 * sizeof(float));
    float* h2  = (float*)(ws + off); off = align256(off + (size_t)N_GRAPHS * 128 * sizeof(float));
    if (off > ws_size) return;  // insufficient workspace -> will fail validation visibly

    // ---- CSR build (once; reused across the 3 layers) ----
    hipMemsetAsync(cnt, 0, (size_t)N_NODES * sizeof(int), stream);
    hist_dst<<<(N_EDGES + 255) / 256, 256, 0, stream>>>(dstE, cnt);
    scan_rows<<<1, 1024, 0, stream>>>(cnt, row_start, cursor);
    fill_csr<<<(N_EDGES + 255) / 256, 256, 0, stream>>>(srcE, dstE, cursor, colI);
    find_gstart<<<1, 128, 0, stream>>>(batch, gstart);

    // ---- 3 conv layers ----
    for (int i = 0; i < 3; ++i) {
        const float* Xin = (i == 0) ? x : H;
        gemm_kqvs<<<N_NODES / 8, 128, 0, stream>>>(
            Xin,
            Wk + (size_t)i * D * D, bk + i * D,
            Wq + (size_t)i * D * D, bq + i * D,
            Wv + (size_t)i * D * D, bv + i * D,
            Ws + (size_t)i * D * D, bs + i * D,
            Kb, Qb, Vb, Sb);
        aggregate<<<N_NODES / 2, 256, 0, stream>>>(Kb, Qb, Vb, Sb, row_start, colI, H);
        hipMemsetAsync(fsum, 0, 128 * sizeof(float), stream);
        hipMemsetAsync(fsq, 0, 128 * sizeof(float), stream);
        bn_stats<<<256, 256, 0, stream>>>(H, fsum, fsq);
        bn_apply<<<(N_NODES * D / 4 + 255) / 256, 256, 0, stream>>>(
            H, fsum, fsq, g_cl + i * D, b_cl + i * D);
    }

    // ---- pooling ----
    pool<<<N_GRAPHS, 128, 0, stream>>>(H, gstart, gap, gsp);
    bn_rows<<<1, 128, 0, stream>>>(gap, N_GRAPHS, 128, g_gap, b_gap, h0, 256, 0);
    bn_rows<<<1, 128, 0, stream>>>(gsp, N_GRAPHS, 128, g_gsp, b_gsp, h0, 256, 128);

    // ---- MLP head ----
    gemm_small<<<N_GRAPHS, 256, 0, stream>>>(h0, W1, b1, h1, 256, 256, 1);
    bn_rows<<<1, 256, 0, stream>>>(h1, N_GRAPHS, 256, g1, bt1, h1, 256, 0);
    gemm_small<<<N_GRAPHS, 256, 0, stream>>>(h1, W2, b2, h2, 256, 128, 1);
    bn_rows<<<1, 128, 0, stream>>>(h2, N_GRAPHS, 128, g2, bt2, h2, 128, 0);
    gemm_small<<<N_GRAPHS, 256, 0, stream>>>(h2, Wl, bl, out, 128, 5, 0);
}